// Round 1
// baseline (287.799 us; speedup 1.0000x reference)
//
#include <hip/hip_runtime.h>
#include <hip/hip_bf16.h>

// CrossAttention: B=4, T=2048, T2=1024, C=1024, H=16, D=64
// Pipeline: cast -> transpose weights -> Q/K/V proj (bf16 MFMA GEMM) ->
//           flash attention -> output proj (fp32 out).

typedef __bf16 bf16_t;
typedef __bf16 bf16x8 __attribute__((ext_vector_type(8)));
typedef float f32x4 __attribute__((ext_vector_type(4)));

#define AS1C(p) ((const __attribute__((address_space(1))) void*)(p))
#define AS3(p)  ((__attribute__((address_space(3))) void*)(p))

constexpr int CC  = 1024;
constexpr int HH  = 16;
constexpr int TT  = 2048;
constexpr int TT2 = 1024;
constexpr int BBATCH = 4;

// ---------------- fp32 -> bf16 cast, 8 elems/thread ----------------
__global__ void cast8(const float* __restrict__ in, bf16_t* __restrict__ out, int n8) {
    int i = blockIdx.x * blockDim.x + threadIdx.x;
    int stride = gridDim.x * blockDim.x;
    for (; i < n8; i += stride) {
        const float4* p = (const float4*)in + 2 * (size_t)i;
        float4 a = p[0], b = p[1];
        bf16x8 v;
        v[0] = (bf16_t)a.x; v[1] = (bf16_t)a.y; v[2] = (bf16_t)a.z; v[3] = (bf16_t)a.w;
        v[4] = (bf16_t)b.x; v[5] = (bf16_t)b.y; v[6] = (bf16_t)b.z; v[7] = (bf16_t)b.w;
        *(bf16x8*)(out + (size_t)i * 8) = v;
    }
}

// ------------- weight transpose+cast: Wt[n][k] = W[k][n], 1024x1024 -------------
__global__ __launch_bounds__(256) void transW(const float* __restrict__ W0, const float* __restrict__ W1,
                                              const float* __restrict__ W2, const float* __restrict__ W3,
                                              bf16_t* __restrict__ T0, bf16_t* __restrict__ T1,
                                              bf16_t* __restrict__ T2, bf16_t* __restrict__ T3) {
    __shared__ float tile[32][33];
    const float* W; bf16_t* Tt;
    switch (blockIdx.z) {
        case 0:  W = W0; Tt = T0; break;
        case 1:  W = W1; Tt = T1; break;
        case 2:  W = W2; Tt = T2; break;
        default: W = W3; Tt = T3; break;
    }
    int x = threadIdx.x & 31, y = threadIdx.x >> 5;
    int bx = blockIdx.x * 32, by = blockIdx.y * 32;
    for (int i = 0; i < 4; ++i) {
        int r = y + i * 8;
        tile[r][x] = W[(size_t)(by + r) * 1024 + bx + x];
    }
    __syncthreads();
    for (int i = 0; i < 4; ++i) {
        int r = y + i * 8;
        Tt[(size_t)(bx + r) * 1024 + by + x] = (bf16_t)tile[x][r];
    }
}

// ------------- GEMM: out[M,1024] = A[M,1024] @ Bt[1024,1024]^T + bias, *scale -------------
// m97 structure: 128x128 tile, BK=32, 4 waves (2x2), 4x4 16x16x32 MFMA frags/wave,
// global_load_lds width-16 staging, linear LDS.
template<bool OUT_BF16>
__global__ __launch_bounds__(256) void gemm_bt(const bf16_t* __restrict__ A,
                                               const bf16_t* __restrict__ Bt,
                                               const float* __restrict__ bias,
                                               void* __restrict__ out, float scale) {
    __shared__ __align__(16) bf16_t As[128 * 32];
    __shared__ __align__(16) bf16_t Bs[128 * 32];
    const int tid  = threadIdx.x;
    const int lane = tid & 63;
    const int wave = tid >> 6;
    const int wr = wave >> 1, wc = wave & 1;
    const int l15 = lane & 15, lhi = lane >> 4;
    const int m0 = blockIdx.y * 128;
    const int n0 = blockIdx.x * 128;

    f32x4 acc[4][4] = {};

    for (int k0 = 0; k0 < 1024; k0 += 32) {
        // stage A and B tiles (128x32 bf16 each) via async global->LDS, 16B/lane
        for (int i = 0; i < 2; ++i) {
            int e   = i * 2048 + wave * 512 + lane * 8;  // element index in tile
            int row = e >> 5, col = e & 31;
            __builtin_amdgcn_global_load_lds(AS1C(A  + (size_t)(m0 + row) * 1024 + k0 + col),
                                             AS3(As + i * 2048 + wave * 512), 16, 0, 0);
            __builtin_amdgcn_global_load_lds(AS1C(Bt + (size_t)(n0 + row) * 1024 + k0 + col),
                                             AS3(Bs + i * 2048 + wave * 512), 16, 0, 0);
        }
        __syncthreads();
        bf16x8 a[4], b[4];
        #pragma unroll
        for (int m = 0; m < 4; ++m)
            a[m] = *(const bf16x8*)&As[(wr * 64 + m * 16 + l15) * 32 + lhi * 8];
        #pragma unroll
        for (int n = 0; n < 4; ++n)
            b[n] = *(const bf16x8*)&Bs[(wc * 64 + n * 16 + l15) * 32 + lhi * 8];
        #pragma unroll
        for (int m = 0; m < 4; ++m)
            #pragma unroll
            for (int n = 0; n < 4; ++n)
                acc[m][n] = __builtin_amdgcn_mfma_f32_16x16x32_bf16(a[m], b[n], acc[m][n], 0, 0, 0);
        __syncthreads();
    }

    // epilogue: +bias, *scale; C/D layout col=lane&15, row=(lane>>4)*4+reg
    #pragma unroll
    for (int n = 0; n < 4; ++n) {
        int col = n0 + wc * 64 + n * 16 + l15;
        float bv = bias[col];
        #pragma unroll
        for (int m = 0; m < 4; ++m) {
            int rowb = m0 + wr * 64 + m * 16 + lhi * 4;
            #pragma unroll
            for (int r = 0; r < 4; ++r) {
                float v = (acc[m][n][r] + bv) * scale;
                if (OUT_BF16)
                    ((bf16_t*)out)[(size_t)(rowb + r) * 1024 + col] = (bf16_t)v;
                else
                    ((float*)out)[(size_t)(rowb + r) * 1024 + col] = v;
            }
        }
    }
}

// ------------- flash attention -------------
// Q already scaled by 1/8*log2e. Layouts: Q/K/V/Y are [B*T(2), C] with head h at cols [h*64, h*64+64).
// Block: 4 waves, each owns 16 q rows (QBLK=64). KV tile = 64 keys.
__global__ __launch_bounds__(256) void attn(const bf16_t* __restrict__ Q,
                                            const bf16_t* __restrict__ K,
                                            const bf16_t* __restrict__ V,
                                            bf16_t* __restrict__ Y) {
    __shared__ __align__(16) bf16_t VT[64 * 64];      // V^T tile: VT[d][k]
    __shared__ __align__(16) bf16_t P[4][16 * 64];    // per-wave P tile [q][k]
    const int tid  = threadIdx.x;
    const int lane = tid & 63;
    const int wave = tid >> 6;
    const int l15 = lane & 15, lhi = lane >> 4;
    const int bh = blockIdx.y;
    const int b = bh >> 4, h = bh & 15;
    const int q0 = blockIdx.x * 64 + wave * 16;

    const bf16_t* Qb = Q + (size_t)b * TT  * CC + h * 64;
    const bf16_t* Kb = K + (size_t)b * TT2 * CC + h * 64;
    const bf16_t* Vb = V + (size_t)b * TT2 * CC + h * 64;

    // A-fragments of Q (16 rows x 64 d), kept in registers
    bf16x8 aq[2];
    #pragma unroll
    for (int ks = 0; ks < 2; ++ks)
        aq[ks] = *(const bf16x8*)&Qb[(size_t)(q0 + l15) * CC + ks * 32 + lhi * 8];

    f32x4 yac[4] = {};
    float mreg[4], lreg[4];
    #pragma unroll
    for (int r = 0; r < 4; ++r) { mreg[r] = -3e38f; lreg[r] = 0.f; }

    const int vk = tid >> 2;          // 0..63: key row this thread stages
    const int vd = (tid & 3) * 16;    // d-segment

    for (int kv0 = 0; kv0 < TT2; kv0 += 64) {
        __syncthreads();
        { // stage V tile transposed into LDS
            const bf16_t* src = &Vb[(size_t)(kv0 + vk) * CC + vd];
            bf16x8 v0 = *(const bf16x8*)(src);
            bf16x8 v1 = *(const bf16x8*)(src + 8);
            #pragma unroll
            for (int i = 0; i < 8; ++i) VT[(vd + i) * 64 + vk] = v0[i];
            #pragma unroll
            for (int i = 0; i < 8; ++i) VT[(vd + 8 + i) * 64 + vk] = v1[i];
        }
        __syncthreads();

        // S = Q K^T  (4 key sub-tiles of 16)
        f32x4 s[4];
        #pragma unroll
        for (int kt = 0; kt < 4; ++kt) {
            f32x4 acc = {};
            #pragma unroll
            for (int ks = 0; ks < 2; ++ks) {
                bf16x8 bk = *(const bf16x8*)&Kb[(size_t)(kv0 + kt * 16 + l15) * CC + ks * 32 + lhi * 8];
                acc = __builtin_amdgcn_mfma_f32_16x16x32_bf16(aq[ks], bk, acc, 0, 0, 0);
            }
            s[kt] = acc;
        }

        // online softmax (rows live across 16-lane groups; reduce with shfl_xor)
        float p[4][4];
        #pragma unroll
        for (int r = 0; r < 4; ++r) {
            float v = fmaxf(fmaxf(s[0][r], s[1][r]), fmaxf(s[2][r], s[3][r]));
            #pragma unroll
            for (int off = 1; off < 16; off <<= 1)
                v = fmaxf(v, __shfl_xor(v, off, 64));
            float mn = fmaxf(mreg[r], v);
            float sc = exp2f(mreg[r] - mn);
            mreg[r] = mn;
            float rs = 0.f;
            #pragma unroll
            for (int kt = 0; kt < 4; ++kt) {
                p[kt][r] = exp2f(s[kt][r] - mn);
                rs += p[kt][r];
            }
            #pragma unroll
            for (int off = 1; off < 16; off <<= 1)
                rs += __shfl_xor(rs, off, 64);
            lreg[r] = lreg[r] * sc + rs;
            #pragma unroll
            for (int dt = 0; dt < 4; ++dt) yac[dt][r] *= sc;
        }

        // P -> LDS (own wave region), then reload as A-fragments
        bf16_t* Pw = P[wave];
        #pragma unroll
        for (int kt = 0; kt < 4; ++kt)
            #pragma unroll
            for (int r = 0; r < 4; ++r)
                Pw[(lhi * 4 + r) * 64 + kt * 16 + l15] = (bf16_t)p[kt][r];

        bf16x8 pa[2];
        #pragma unroll
        for (int ks = 0; ks < 2; ++ks)
            pa[ks] = *(const bf16x8*)&Pw[l15 * 64 + ks * 32 + lhi * 8];

        // Y += P V
        #pragma unroll
        for (int dt = 0; dt < 4; ++dt) {
            #pragma unroll
            for (int ks = 0; ks < 2; ++ks) {
                bf16x8 bv = *(const bf16x8*)&VT[(dt * 16 + l15) * 64 + ks * 32 + lhi * 8];
                yac[dt] = __builtin_amdgcn_mfma_f32_16x16x32_bf16(pa[ks], bv, yac[dt], 0, 0, 0);
            }
        }
    }

    // epilogue: divide by softmax denom, store bf16
    bf16_t* Yb = Y + (size_t)b * TT * CC + h * 64;
    #pragma unroll
    for (int r = 0; r < 4; ++r) {
        float inv = 1.f / lreg[r];
        int qr = q0 + lhi * 4 + r;
        #pragma unroll
        for (int dt = 0; dt < 4; ++dt)
            Yb[(size_t)qr * CC + dt * 16 + l15] = (bf16_t)(yac[dt][r] * inv);
    }
}

extern "C" void kernel_launch(void* const* d_in, const int* in_sizes, int n_in,
                              void* d_out, int out_size, void* d_ws, size_t ws_size,
                              hipStream_t stream) {
    const float* x   = (const float*)d_in[0];
    const float* enc = (const float*)d_in[1];
    const float* Wq  = (const float*)d_in[2];
    const float* bq  = (const float*)d_in[3];
    const float* Wk  = (const float*)d_in[4];
    const float* bk  = (const float*)d_in[5];
    const float* Wv  = (const float*)d_in[6];
    const float* bv  = (const float*)d_in[7];
    const float* Wo  = (const float*)d_in[8];
    const float* bo  = (const float*)d_in[9];
    float* out = (float*)d_out;

    char* w = (char*)d_ws;
    size_t o = 0;
    bf16_t* xb  = (bf16_t*)(w + o); o += (size_t)8192 * 1024 * 2;
    bf16_t* eb  = (bf16_t*)(w + o); o += (size_t)4096 * 1024 * 2;
    bf16_t* wtq = (bf16_t*)(w + o); o += (size_t)1024 * 1024 * 2;
    bf16_t* wtk = (bf16_t*)(w + o); o += (size_t)1024 * 1024 * 2;
    bf16_t* wtv = (bf16_t*)(w + o); o += (size_t)1024 * 1024 * 2;
    bf16_t* wto = (bf16_t*)(w + o); o += (size_t)1024 * 1024 * 2;
    bf16_t* Qs  = (bf16_t*)(w + o); o += (size_t)8192 * 1024 * 2;
    bf16_t* Ks  = (bf16_t*)(w + o); o += (size_t)4096 * 1024 * 2;
    bf16_t* Vs  = (bf16_t*)(w + o); o += (size_t)4096 * 1024 * 2;
    bf16_t* yb  = (bf16_t*)(w + o); o += (size_t)8192 * 1024 * 2;

    cast8<<<2048, 256, 0, stream>>>(x,   xb, 8192 * 1024 / 8);
    cast8<<<1024, 256, 0, stream>>>(enc, eb, 4096 * 1024 / 8);
    transW<<<dim3(32, 32, 4), 256, 0, stream>>>(Wq, Wk, Wv, Wo, wtq, wtk, wtv, wto);

    // fold softmax scale (1/sqrt(64)) and log2(e) into Q so attention uses exp2
    const float qscale = 0.125f * 1.4426950408889634f;
    gemm_bt<true><<<dim3(8, 64), 256, 0, stream>>>(xb, wtq, bq, (void*)Qs, qscale);
    gemm_bt<true><<<dim3(8, 32), 256, 0, stream>>>(eb, wtk, bk, (void*)Ks, 1.0f);
    gemm_bt<true><<<dim3(8, 32), 256, 0, stream>>>(eb, wtv, bv, (void*)Vs, 1.0f);

    attn<<<dim3(TT / 64, BBATCH * HH), 256, 0, stream>>>(Qs, Ks, Vs, yb);

    gemm_bt<false><<<dim3(8, 64), 256, 0, stream>>>(yb, wto, bo, d_out, 1.0f);
}

// Round 2
// 191.694 us; speedup vs baseline: 1.5013x; 1.5013x over previous
//
#include <hip/hip_runtime.h>
#include <hip/hip_bf16.h>

// CrossAttention: B=4, T=2048, T2=1024, C=1024, H=16, D=64
// cast -> transpose weights -> Q/K/V proj (bf16 MFMA GEMM) -> V transpose ->
// flash attention (swapped 32x32 MFMA, in-register softmax) -> output proj.

typedef __bf16 bf16_t;
typedef __bf16 bf16x8 __attribute__((ext_vector_type(8)));
typedef float f32x4 __attribute__((ext_vector_type(4)));
typedef float f32x16 __attribute__((ext_vector_type(16)));
typedef unsigned int u32x4 __attribute__((ext_vector_type(4)));

#define AS1C(p) ((const __attribute__((address_space(1))) void*)(p))
#define AS3(p)  ((__attribute__((address_space(3))) void*)(p))

constexpr int CC  = 1024;
constexpr int TT  = 2048;
constexpr int TT2 = 1024;
constexpr int BBATCH = 4;

// ---------------- fp32 -> bf16 cast, 8 elems/thread ----------------
__global__ void cast8(const float* __restrict__ in, bf16_t* __restrict__ out, int n8) {
    int i = blockIdx.x * blockDim.x + threadIdx.x;
    int stride = gridDim.x * blockDim.x;
    for (; i < n8; i += stride) {
        const float4* p = (const float4*)in + 2 * (size_t)i;
        float4 a = p[0], b = p[1];
        bf16x8 v;
        v[0] = (bf16_t)a.x; v[1] = (bf16_t)a.y; v[2] = (bf16_t)a.z; v[3] = (bf16_t)a.w;
        v[4] = (bf16_t)b.x; v[5] = (bf16_t)b.y; v[6] = (bf16_t)b.z; v[7] = (bf16_t)b.w;
        *(bf16x8*)(out + (size_t)i * 8) = v;
    }
}

// ------------- weight transpose+cast: Wt[n][k] = W[k][n], 1024x1024 -------------
__global__ __launch_bounds__(256) void transW(const float* __restrict__ W0, const float* __restrict__ W1,
                                              const float* __restrict__ W2, const float* __restrict__ W3,
                                              bf16_t* __restrict__ T0, bf16_t* __restrict__ T1,
                                              bf16_t* __restrict__ T2, bf16_t* __restrict__ T3) {
    __shared__ float tile[32][33];
    const float* W; bf16_t* Tt;
    switch (blockIdx.z) {
        case 0:  W = W0; Tt = T0; break;
        case 1:  W = W1; Tt = T1; break;
        case 2:  W = W2; Tt = T2; break;
        default: W = W3; Tt = T3; break;
    }
    int x = threadIdx.x & 31, y = threadIdx.x >> 5;
    int bx = blockIdx.x * 32, by = blockIdx.y * 32;
    for (int i = 0; i < 4; ++i) {
        int r = y + i * 8;
        tile[r][x] = W[(size_t)(by + r) * 1024 + bx + x];
    }
    __syncthreads();
    for (int i = 0; i < 4; ++i) {
        int r = y + i * 8;
        Tt[(size_t)(bx + r) * 1024 + by + x] = (bf16_t)tile[x][r];
    }
}

// ------------- GEMM: out[M,1024] = A[M,1024] @ Bt[1024,1024]^T + bias, *scale -------------
template<bool OUT_BF16>
__global__ __launch_bounds__(256) void gemm_bt(const bf16_t* __restrict__ A,
                                               const bf16_t* __restrict__ Bt,
                                               const float* __restrict__ bias,
                                               void* __restrict__ out, float scale) {
    __shared__ __align__(16) bf16_t As[128 * 32];
    __shared__ __align__(16) bf16_t Bs[128 * 32];
    const int tid  = threadIdx.x;
    const int lane = tid & 63;
    const int wave = tid >> 6;
    const int wr = wave >> 1, wc = wave & 1;
    const int l15 = lane & 15, lhi = lane >> 4;
    const int m0 = blockIdx.y * 128;
    const int n0 = blockIdx.x * 128;

    f32x4 acc[4][4] = {};

    for (int k0 = 0; k0 < 1024; k0 += 32) {
        for (int i = 0; i < 2; ++i) {
            int e   = i * 2048 + wave * 512 + lane * 8;
            int row = e >> 5, col = e & 31;
            __builtin_amdgcn_global_load_lds(AS1C(A  + (size_t)(m0 + row) * 1024 + k0 + col),
                                             AS3(As + i * 2048 + wave * 512), 16, 0, 0);
            __builtin_amdgcn_global_load_lds(AS1C(Bt + (size_t)(n0 + row) * 1024 + k0 + col),
                                             AS3(Bs + i * 2048 + wave * 512), 16, 0, 0);
        }
        __syncthreads();
        bf16x8 a[4], b[4];
        #pragma unroll
        for (int m = 0; m < 4; ++m)
            a[m] = *(const bf16x8*)&As[(wr * 64 + m * 16 + l15) * 32 + lhi * 8];
        #pragma unroll
        for (int n = 0; n < 4; ++n)
            b[n] = *(const bf16x8*)&Bs[(wc * 64 + n * 16 + l15) * 32 + lhi * 8];
        #pragma unroll
        for (int m = 0; m < 4; ++m)
            #pragma unroll
            for (int n = 0; n < 4; ++n)
                acc[m][n] = __builtin_amdgcn_mfma_f32_16x16x32_bf16(a[m], b[n], acc[m][n], 0, 0, 0);
        __syncthreads();
    }

    #pragma unroll
    for (int n = 0; n < 4; ++n) {
        int col = n0 + wc * 64 + n * 16 + l15;
        float bv = bias[col];
        #pragma unroll
        for (int m = 0; m < 4; ++m) {
            int rowb = m0 + wr * 64 + m * 16 + lhi * 4;
            #pragma unroll
            for (int r = 0; r < 4; ++r) {
                float v = (acc[m][n][r] + bv) * scale;
                if (OUT_BF16)
                    ((bf16_t*)out)[(size_t)(rowb + r) * 1024 + col] = (bf16_t)v;
                else
                    ((float*)out)[(size_t)(rowb + r) * 1024 + col] = v;
            }
        }
    }
}

// ------------- V transpose per head: Vt[bh][d][key] = Vs[b*1024+key][h*64+d] -------------
__global__ __launch_bounds__(256) void vtrans(const bf16_t* __restrict__ Vs, bf16_t* __restrict__ Vt) {
    __shared__ bf16_t t[64][72];
    int bh = blockIdx.y, b = bh >> 4, h = bh & 15;
    int kv0 = blockIdx.x * 64;
    int r = threadIdx.x >> 2, c0 = (threadIdx.x & 3) * 16;
    const bf16_t* src = Vs + (size_t)(b * 1024 + kv0 + r) * 1024 + h * 64 + c0;
    *(bf16x8*)&t[r][c0]     = *(const bf16x8*)src;
    *(bf16x8*)&t[r][c0 + 8] = *(const bf16x8*)(src + 8);
    __syncthreads();
    int d = threadIdx.x >> 2, k0 = (threadIdx.x & 3) * 16;
    bf16x8 v0, v1;
    #pragma unroll
    for (int j = 0; j < 8; ++j) { v0[j] = t[k0 + j][d]; v1[j] = t[k0 + 8 + j][d]; }
    bf16_t* dst = Vt + ((size_t)bh * 64 + d) * 1024 + kv0 + k0;
    *(bf16x8*)dst       = v0;
    *(bf16x8*)(dst + 8) = v1;
}

// ---------------- flash attention, swapped 32x32 ----------------
// S^T = mfma(A=K rows, B=Q rows): lane owns q = l&31 column -> in-register softmax.
// Y^T = mfma(A=V^T rows, B=P rows). K and V^T staged in LDS with XOR swizzle.
__device__ inline unsigned pk_bf16(float lo, float hi) {
    unsigned r;
    asm("v_cvt_pk_bf16_f32 %0, %1, %2" : "=v"(r) : "v"(lo), "v"(hi));
    return r;
}
__device__ inline void swap32(unsigned &a, unsigned &b) {
    asm("v_permlane32_swap_b32 %0, %1" : "+v"(a), "+v"(b));
}
__device__ inline bf16x8 ldsf(const bf16_t* base, int row, int colb) {
    int off = row * 128 + (colb ^ ((row & 7) << 4));
    return *(const bf16x8*)((const char*)base + off);
}

__global__ __launch_bounds__(512) void attn512(const bf16_t* __restrict__ Q,
                                               const bf16_t* __restrict__ K,
                                               const bf16_t* __restrict__ Vt,
                                               bf16_t* __restrict__ Y) {
    __shared__ __align__(16) bf16_t Kl[64 * 64];
    __shared__ __align__(16) bf16_t Vl[64 * 64];
    __shared__ __align__(16) bf16_t Ob[8][32 * 64];

    const int tid = threadIdx.x;
    const int l   = tid & 63;
    const int w   = tid >> 6;
    const int l31 = l & 31;
    const int lh  = l >> 5;

    const int bid = blockIdx.x;
    const int bh  = bid & 63;          // low bits -> same head stays on one XCD
    const int qb  = bid >> 6;
    const int b = bh >> 4, h = bh & 15;
    const int q0 = qb * 256 + w * 32;

    const bf16_t* Qb = Q  + (size_t)b * TT  * CC + h * 64;
    const bf16_t* Kb = K  + (size_t)b * TT2 * CC + h * 64;
    const bf16_t* Vb = Vt + (size_t)bh * 64 * 1024;

    // Q B-frags (rows of Q), kept in registers
    bf16x8 qf[4];
    #pragma unroll
    for (int kt = 0; kt < 4; ++kt)
        qf[kt] = *(const bf16x8*)&Qb[(size_t)(q0 + l31) * CC + kt * 16 + lh * 8];

    f32x16 y0 = {}, y1 = {};
    float m = -3e38f, ls = 0.f;

    // staging: wave w stages rows w*8..w*8+7, pre-swizzled global source (linear LDS dest)
    const int srow  = l >> 3;
    const int scolb = ((l & 7) * 16) ^ (srow << 4);
    const char* Ksrc = (const char*)Kb + (size_t)(w * 8 + srow) * 2048 + scolb;
    const char* Vsrc = (const char*)Vb + (size_t)(w * 8 + srow) * 2048 + scolb;

    for (int kv0 = 0; kv0 < TT2; kv0 += 64) {
        __syncthreads();
        __builtin_amdgcn_global_load_lds(AS1C(Ksrc + (size_t)kv0 * 2048), AS3((char*)Kl + w * 1024), 16, 0, 0);
        __builtin_amdgcn_global_load_lds(AS1C(Vsrc + kv0 * 2),            AS3((char*)Vl + w * 1024), 16, 0, 0);
        __syncthreads();

        // S^T = K · Q^T  (two 32-key tiles)
        f32x16 s0 = {}, s1 = {};
        #pragma unroll
        for (int kt = 0; kt < 4; ++kt) {
            int colb = kt * 32 + (lh << 4);
            bf16x8 a0 = ldsf(Kl, l31,      colb);
            bf16x8 a1 = ldsf(Kl, 32 + l31, colb);
            s0 = __builtin_amdgcn_mfma_f32_32x32x16_bf16(a0, qf[kt], s0, 0, 0, 0);
            s1 = __builtin_amdgcn_mfma_f32_32x32x16_bf16(a1, qf[kt], s1, 0, 0, 0);
        }

        // online softmax: lane-local over 32 regs + one cross-half exchange
        float pm = fmaxf(s0[0], s1[0]);
        #pragma unroll
        for (int r = 1; r < 16; ++r) pm = fmaxf(pm, fmaxf(s0[r], s1[r]));
        pm = fmaxf(pm, __shfl_xor(pm, 32, 64));
        float mn = fmaxf(m, pm);
        float sc = exp2f(m - mn);
        m = mn;
        float rs = 0.f;
        #pragma unroll
        for (int r = 0; r < 16; ++r) {
            float p0 = exp2f(s0[r] - mn);
            float p1 = exp2f(s1[r] - mn);
            s0[r] = p0; s1[r] = p1;
            rs += p0 + p1;
        }
        rs += __shfl_xor(rs, 32, 64);
        ls = ls * sc + rs;
        #pragma unroll
        for (int r = 0; r < 16; ++r) { y0[r] *= sc; y1[r] *= sc; }

        // PV: per 16-key tile, pack P in-register (cvt_pk + permlane32_swap), mfma
        #pragma unroll
        for (int kt = 0; kt < 4; ++kt) {
            const f32x16& sp = (kt < 2) ? s0 : s1;
            const int rb = (kt & 1) * 8;
            unsigned a0 = pk_bf16(sp[rb + 0], sp[rb + 1]);
            unsigned a1 = pk_bf16(sp[rb + 2], sp[rb + 3]);
            unsigned a2 = pk_bf16(sp[rb + 4], sp[rb + 5]);
            unsigned a3 = pk_bf16(sp[rb + 6], sp[rb + 7]);
            swap32(a0, a2);
            swap32(a1, a3);
            union { u32x4 u; bf16x8 h; } cv;
            cv.u = (u32x4){a0, a1, a2, a3};
            int colb = kt * 32 + (lh << 4);
            bf16x8 v0 = ldsf(Vl, l31,      colb);
            bf16x8 v1 = ldsf(Vl, 32 + l31, colb);
            y0 = __builtin_amdgcn_mfma_f32_32x32x16_bf16(v0, cv.h, y0, 0, 0, 0);
            y1 = __builtin_amdgcn_mfma_f32_32x32x16_bf16(v1, cv.h, y1, 0, 0, 0);
        }
    }

    // epilogue: divide (lane-local), per-wave LDS transpose, coalesced store
    float invl = 1.f / ls;
    bf16_t* ob = Ob[w];
    #pragma unroll
    for (int r = 0; r < 16; ++r) {
        int drow = (r & 3) + 8 * (r >> 2) + 4 * lh;
        int sw = (l31 & 7) << 4;
        *(bf16_t*)((char*)ob + l31 * 128 + ((drow * 2) ^ sw))        = (bf16_t)(y0[r] * invl);
        *(bf16_t*)((char*)ob + l31 * 128 + (((32 + drow) * 2) ^ sw)) = (bf16_t)(y1[r] * invl);
    }
    __syncthreads();
    bf16_t* Yb = Y + (size_t)b * TT * CC + h * 64;
    #pragma unroll
    for (int i = 0; i < 4; ++i) {
        int qr = i * 8 + (l >> 3);      // row within this wave's 32
        int c  = ((l & 7) * 16) ^ ((qr & 7) << 4);
        bf16x8 v = *(const bf16x8*)((const char*)ob + qr * 128 + c);
        *(bf16x8*)&Yb[(size_t)(q0 + qr) * CC + (l & 7) * 8] = v;
    }
}

extern "C" void kernel_launch(void* const* d_in, const int* in_sizes, int n_in,
                              void* d_out, int out_size, void* d_ws, size_t ws_size,
                              hipStream_t stream) {
    const float* x   = (const float*)d_in[0];
    const float* enc = (const float*)d_in[1];
    const float* Wq  = (const float*)d_in[2];
    const float* bq  = (const float*)d_in[3];
    const float* Wk  = (const float*)d_in[4];
    const float* bk  = (const float*)d_in[5];
    const float* Wv  = (const float*)d_in[6];
    const float* bv  = (const float*)d_in[7];
    const float* Wo  = (const float*)d_in[8];
    const float* bo  = (const float*)d_in[9];

    char* w = (char*)d_ws;
    size_t o = 0;
    bf16_t* xb  = (bf16_t*)(w + o); o += (size_t)8192 * 1024 * 2;
    bf16_t* eb  = (bf16_t*)(w + o); o += (size_t)4096 * 1024 * 2;
    bf16_t* wtq = (bf16_t*)(w + o); o += (size_t)1024 * 1024 * 2;
    bf16_t* wtk = (bf16_t*)(w + o); o += (size_t)1024 * 1024 * 2;
    bf16_t* wtv = (bf16_t*)(w + o); o += (size_t)1024 * 1024 * 2;
    bf16_t* wto = (bf16_t*)(w + o); o += (size_t)1024 * 1024 * 2;
    bf16_t* Qs  = (bf16_t*)(w + o); o += (size_t)8192 * 1024 * 2;
    bf16_t* Ks  = (bf16_t*)(w + o); o += (size_t)4096 * 1024 * 2;
    bf16_t* Vs  = (bf16_t*)(w + o); o += (size_t)4096 * 1024 * 2;
    bf16_t* yb  = (bf16_t*)(w + o); o += (size_t)8192 * 1024 * 2;
    bf16_t* Vt  = eb;   // eb is dead after the V projection; reuse for V^T (8 MB)

    cast8<<<2048, 256, 0, stream>>>(x,   xb, 8192 * 1024 / 8);
    cast8<<<1024, 256, 0, stream>>>(enc, eb, 4096 * 1024 / 8);
    transW<<<dim3(32, 32, 4), 256, 0, stream>>>(Wq, Wk, Wv, Wo, wtq, wtk, wtv, wto);

    // fold softmax scale (1/sqrt(64)) and log2(e) into Q so attention uses exp2
    const float qscale = 0.125f * 1.4426950408889634f;
    gemm_bt<true><<<dim3(8, 64), 256, 0, stream>>>(xb, wtq, bq, (void*)Qs, qscale);
    gemm_bt<true><<<dim3(8, 32), 256, 0, stream>>>(eb, wtk, bk, (void*)Ks, 1.0f);
    gemm_bt<true><<<dim3(8, 32), 256, 0, stream>>>(eb, wtv, bv, (void*)Vs, 1.0f);

    vtrans<<<dim3(16, 64), 256, 0, stream>>>(Vs, Vt);

    attn512<<<512, 512, 0, stream>>>(Qs, Ks, Vt, yb);

    gemm_bt<false><<<dim3(8, 64), 256, 0, stream>>>(yb, wto, bo, d_out, 1.0f);
}

// Round 3
// 160.055 us; speedup vs baseline: 1.7981x; 1.1977x over previous
//
#include <hip/hip_runtime.h>
#include <hip/hip_bf16.h>

// CrossAttention: B=4, T=2048, T2=1024, C=1024, H=16, D=64
// cast -> transpose weights -> Q proj, fused K/V proj (bf16 MFMA GEMM) ->
// V transpose -> flash attention (swapped 32x32, dbuf pipeline, defer-max) ->
// output proj.

typedef __bf16 bf16_t;
typedef __bf16 bf16x8 __attribute__((ext_vector_type(8)));
typedef float f32x4 __attribute__((ext_vector_type(4)));
typedef float f32x16 __attribute__((ext_vector_type(16)));
typedef unsigned int u32x4 __attribute__((ext_vector_type(4)));

#define AS1C(p) ((const __attribute__((address_space(1))) void*)(p))
#define AS3(p)  ((__attribute__((address_space(3))) void*)(p))

constexpr int CC  = 1024;
constexpr int TT  = 2048;
constexpr int TT2 = 1024;
constexpr int BBATCH = 4;

// ---------------- fp32 -> bf16 cast, 8 elems/thread ----------------
__global__ void cast8(const float* __restrict__ in, bf16_t* __restrict__ out, int n8) {
    int i = blockIdx.x * blockDim.x + threadIdx.x;
    int stride = gridDim.x * blockDim.x;
    for (; i < n8; i += stride) {
        const float4* p = (const float4*)in + 2 * (size_t)i;
        float4 a = p[0], b = p[1];
        bf16x8 v;
        v[0] = (bf16_t)a.x; v[1] = (bf16_t)a.y; v[2] = (bf16_t)a.z; v[3] = (bf16_t)a.w;
        v[4] = (bf16_t)b.x; v[5] = (bf16_t)b.y; v[6] = (bf16_t)b.z; v[7] = (bf16_t)b.w;
        *(bf16x8*)(out + (size_t)i * 8) = v;
    }
}

// ------------- weight transpose+cast: Wt[n][k] = W[k][n], 1024x1024 -------------
__global__ __launch_bounds__(256) void transW(const float* __restrict__ W0, const float* __restrict__ W1,
                                              const float* __restrict__ W2, const float* __restrict__ W3,
                                              bf16_t* __restrict__ T0, bf16_t* __restrict__ T1,
                                              bf16_t* __restrict__ T2, bf16_t* __restrict__ T3) {
    __shared__ float tile[32][33];
    const float* W; bf16_t* Tt;
    switch (blockIdx.z) {
        case 0:  W = W0; Tt = T0; break;
        case 1:  W = W1; Tt = T1; break;
        case 2:  W = W2; Tt = T2; break;
        default: W = W3; Tt = T3; break;
    }
    int x = threadIdx.x & 31, y = threadIdx.x >> 5;
    int bx = blockIdx.x * 32, by = blockIdx.y * 32;
    for (int i = 0; i < 4; ++i) {
        int r = y + i * 8;
        tile[r][x] = W[(size_t)(by + r) * 1024 + bx + x];
    }
    __syncthreads();
    for (int i = 0; i < 4; ++i) {
        int r = y + i * 8;
        Tt[(size_t)(bx + r) * 1024 + by + x] = (bf16_t)tile[x][r];
    }
}

// ------------- GEMM: out[M,N] = A[M,1024] @ Bt[N,1024]^T + bias, *scale -------------
// m97 structure, 1-D grid with bijective XCD swizzle. SPLIT: cols<1024 -> outA, else outB.
template<bool OUT_BF16, bool SPLIT>
__global__ __launch_bounds__(256) void gemm_bt(const bf16_t* __restrict__ A,
                                               const bf16_t* __restrict__ Bt,
                                               const float* __restrict__ biasA,
                                               const float* __restrict__ biasB,
                                               void* __restrict__ outA,
                                               void* __restrict__ outB,
                                               float scale, int lgNT, int mband) {
    __shared__ __align__(16) bf16_t As[128 * 32];
    __shared__ __align__(16) bf16_t Bs[128 * 32];
    const int tid  = threadIdx.x;
    const int lane = tid & 63;
    const int wave = tid >> 6;
    const int wr = wave >> 1, wc = wave & 1;
    const int l15 = lane & 15, lhi = lane >> 4;

    // XCD-aware decode: blocks with same (bid&7) share one XCD -> give each an m-band
    const int bid = blockIdx.x;
    const int xcd = bid & 7;
    const int j   = bid >> 3;
    const int n0  = (j & ((1 << lgNT) - 1)) * 128;
    const int m0  = (xcd * mband + (j >> lgNT)) * 128;

    f32x4 acc[4][4] = {};

    for (int k0 = 0; k0 < 1024; k0 += 32) {
        for (int i = 0; i < 2; ++i) {
            int e   = i * 2048 + wave * 512 + lane * 8;
            int row = e >> 5, col = e & 31;
            __builtin_amdgcn_global_load_lds(AS1C(A  + (size_t)(m0 + row) * 1024 + k0 + col),
                                             AS3(As + i * 2048 + wave * 512), 16, 0, 0);
            __builtin_amdgcn_global_load_lds(AS1C(Bt + (size_t)(n0 + row) * 1024 + k0 + col),
                                             AS3(Bs + i * 2048 + wave * 512), 16, 0, 0);
        }
        __syncthreads();
        bf16x8 a[4], b[4];
        #pragma unroll
        for (int m = 0; m < 4; ++m)
            a[m] = *(const bf16x8*)&As[(wr * 64 + m * 16 + l15) * 32 + lhi * 8];
        #pragma unroll
        for (int n = 0; n < 4; ++n)
            b[n] = *(const bf16x8*)&Bs[(wc * 64 + n * 16 + l15) * 32 + lhi * 8];
        #pragma unroll
        for (int m = 0; m < 4; ++m)
            #pragma unroll
            for (int n = 0; n < 4; ++n)
                acc[m][n] = __builtin_amdgcn_mfma_f32_16x16x32_bf16(a[m], b[n], acc[m][n], 0, 0, 0);
        __syncthreads();
    }

    #pragma unroll
    for (int n = 0; n < 4; ++n) {
        int col = n0 + wc * 64 + n * 16 + l15;
        const float* bias = biasA;
        void* out = outA;
        if (SPLIT && col >= 1024) { bias = biasB; out = outB; col -= 1024; }
        float bv = bias[col];
        #pragma unroll
        for (int m = 0; m < 4; ++m) {
            int rowb = m0 + wr * 64 + m * 16 + lhi * 4;
            #pragma unroll
            for (int r = 0; r < 4; ++r) {
                float v = (acc[m][n][r] + bv) * scale;
                if (OUT_BF16)
                    ((bf16_t*)out)[(size_t)(rowb + r) * 1024 + col] = (bf16_t)v;
                else
                    ((float*)out)[(size_t)(rowb + r) * 1024 + col] = v;
            }
        }
    }
}

// ------------- V transpose per head: Vt[bh][d][key] = Vs[b*1024+key][h*64+d] -------------
__global__ __launch_bounds__(256) void vtrans(const bf16_t* __restrict__ Vs, bf16_t* __restrict__ Vt) {
    __shared__ bf16_t t[64][72];
    int bh = blockIdx.y, b = bh >> 4, h = bh & 15;
    int kv0 = blockIdx.x * 64;
    int r = threadIdx.x >> 2, c0 = (threadIdx.x & 3) * 16;
    const bf16_t* src = Vs + (size_t)(b * 1024 + kv0 + r) * 1024 + h * 64 + c0;
    *(bf16x8*)&t[r][c0]     = *(const bf16x8*)src;
    *(bf16x8*)&t[r][c0 + 8] = *(const bf16x8*)(src + 8);
    __syncthreads();
    int d = threadIdx.x >> 2, k0 = (threadIdx.x & 3) * 16;
    bf16x8 v0, v1;
    #pragma unroll
    for (int j = 0; j < 8; ++j) { v0[j] = t[k0 + j][d]; v1[j] = t[k0 + 8 + j][d]; }
    bf16_t* dst = Vt + ((size_t)bh * 64 + d) * 1024 + kv0 + k0;
    *(bf16x8*)dst       = v0;
    *(bf16x8*)(dst + 8) = v1;
}

// ---------------- flash attention, swapped 32x32, dbuf pipeline ----------------
__device__ inline unsigned pk_bf16(float lo, float hi) {
    unsigned r;
    asm("v_cvt_pk_bf16_f32 %0, %1, %2" : "=v"(r) : "v"(lo), "v"(hi));
    return r;
}
__device__ inline void swap32(unsigned &a, unsigned &b) {
    asm("v_permlane32_swap_b32 %0, %1" : "+v"(a), "+v"(b));
}
__device__ inline bf16x8 ldsf(const bf16_t* base, int row, int colb) {
    int off = row * 128 + (colb ^ ((row & 7) << 4));
    return *(const bf16x8*)((const char*)base + off);
}

__global__ __launch_bounds__(512) void attn512(const bf16_t* __restrict__ Q,
                                               const bf16_t* __restrict__ K,
                                               const bf16_t* __restrict__ Vt,
                                               bf16_t* __restrict__ Y) {
    // double-buffered K/V stage (2 x (8KB K + 8KB V) = 32KB); epilogue aliases it
    __shared__ __align__(16) bf16_t SMEM[2][2][64 * 64];

    const int tid = threadIdx.x;
    const int l   = tid & 63;
    const int w   = tid >> 6;
    const int l31 = l & 31;
    const int lh  = l >> 5;

    const int bid = blockIdx.x;
    const int bh  = bid & 63;          // low bits -> same head stays on one XCD
    const int qb  = bid >> 6;
    const int b = bh >> 4, h = bh & 15;
    const int q0 = qb * 256 + w * 32;

    const bf16_t* Qb = Q  + (size_t)b * TT  * CC + h * 64;
    const bf16_t* Kb = K  + (size_t)b * TT2 * CC + h * 64;
    const bf16_t* Vb = Vt + (size_t)bh * 64 * 1024;

    // Q B-frags (rows of Q), kept in registers
    bf16x8 qf[4];
    #pragma unroll
    for (int kt = 0; kt < 4; ++kt)
        qf[kt] = *(const bf16x8*)&Qb[(size_t)(q0 + l31) * CC + kt * 16 + lh * 8];

    f32x16 y0 = {}, y1 = {};
    float m = -3e38f, ls = 0.f;

    // staging: wave w stages rows w*8..w*8+7, pre-swizzled global source (linear LDS dest)
    const int srow  = l >> 3;
    const int scolb = ((l & 7) * 16) ^ (srow << 4);
    const char* Ksrc = (const char*)Kb + (size_t)(w * 8 + srow) * 2048 + scolb;
    const char* Vsrc = (const char*)Vb + (size_t)(w * 8 + srow) * 2048 + scolb;

    #define STAGE(t, buf)                                                                        \
        do {                                                                                     \
            __builtin_amdgcn_global_load_lds(AS1C(Ksrc + (size_t)(t) * 131072),                  \
                                             AS3((char*)&SMEM[buf][0][0] + w * 1024), 16, 0, 0); \
            __builtin_amdgcn_global_load_lds(AS1C(Vsrc + (t) * 128),                             \
                                             AS3((char*)&SMEM[buf][1][0] + w * 1024), 16, 0, 0); \
        } while (0)

    constexpr int NT = TT2 / 64;  // 16
    STAGE(0, 0);

    for (int t = 0; t < NT; ++t) {
        const int cur = t & 1;
        if (t + 1 < NT) {
            STAGE(t + 1, cur ^ 1);
            asm volatile("s_waitcnt vmcnt(2)" ::: "memory");   // tile t landed; t+1 in flight
        } else {
            asm volatile("s_waitcnt vmcnt(0)" ::: "memory");
        }
        __builtin_amdgcn_sched_barrier(0);
        __builtin_amdgcn_s_barrier();
        __builtin_amdgcn_sched_barrier(0);

        const bf16_t* Kl = &SMEM[cur][0][0];
        const bf16_t* Vl = &SMEM[cur][1][0];

        // S^T = K · Q^T  (two 32-key tiles)
        f32x16 s0 = {}, s1 = {};
        #pragma unroll
        for (int kt = 0; kt < 4; ++kt) {
            int colb = kt * 32 + (lh << 4);
            bf16x8 a0 = ldsf(Kl, l31,      colb);
            bf16x8 a1 = ldsf(Kl, 32 + l31, colb);
            s0 = __builtin_amdgcn_mfma_f32_32x32x16_bf16(a0, qf[kt], s0, 0, 0, 0);
            s1 = __builtin_amdgcn_mfma_f32_32x32x16_bf16(a1, qf[kt], s1, 0, 0, 0);
        }

        // online softmax: lane-local; defer-max (THR=8) skips the y-rescale
        float pm = fmaxf(s0[0], s1[0]);
        #pragma unroll
        for (int r = 1; r < 16; ++r) pm = fmaxf(fmaxf(pm, s0[r]), s1[r]);   // v_max3 chain
        pm = fmaxf(pm, __shfl_xor(pm, 32, 64));
        if (!__all(pm <= m + 8.f)) {
            float mn = fmaxf(m, pm);
            float sc = exp2f(m - mn);
            m = mn;
            ls *= sc;
            #pragma unroll
            for (int r = 0; r < 16; ++r) { y0[r] *= sc; y1[r] *= sc; }
        }
        float rs = 0.f;
        #pragma unroll
        for (int r = 0; r < 16; ++r) {
            float p0 = exp2f(s0[r] - m);
            float p1 = exp2f(s1[r] - m);
            s0[r] = p0; s1[r] = p1;
            rs += p0 + p1;
        }
        rs += __shfl_xor(rs, 32, 64);
        ls += rs;

        // PV: per 16-key tile, pack P in-register (cvt_pk + permlane32_swap), mfma
        #pragma unroll
        for (int kt = 0; kt < 4; ++kt) {
            const f32x16& sp = (kt < 2) ? s0 : s1;
            const int rb = (kt & 1) * 8;
            unsigned a0 = pk_bf16(sp[rb + 0], sp[rb + 1]);
            unsigned a1 = pk_bf16(sp[rb + 2], sp[rb + 3]);
            unsigned a2 = pk_bf16(sp[rb + 4], sp[rb + 5]);
            unsigned a3 = pk_bf16(sp[rb + 6], sp[rb + 7]);
            swap32(a0, a2);
            swap32(a1, a3);
            union { u32x4 u; bf16x8 h; } cv;
            cv.u = (u32x4){a0, a1, a2, a3};
            int colb = kt * 32 + (lh << 4);
            bf16x8 v0 = ldsf(Vl, l31,      colb);
            bf16x8 v1 = ldsf(Vl, 32 + l31, colb);
            y0 = __builtin_amdgcn_mfma_f32_32x32x16_bf16(v0, cv.h, y0, 0, 0, 0);
            y1 = __builtin_amdgcn_mfma_f32_32x32x16_bf16(v1, cv.h, y1, 0, 0, 0);
        }

        __builtin_amdgcn_s_barrier();   // all waves done reading buf[cur] before overwrite
    }
    #undef STAGE

    __syncthreads();   // safe to alias stage LDS for the output transpose

    // epilogue: divide (lane-local), per-wave LDS transpose, coalesced store
    float invl = 1.f / ls;
    bf16_t* ob = &SMEM[0][0][0] + w * 2048;   // 4KB per wave
    #pragma unroll
    for (int r = 0; r < 16; ++r) {
        int drow = (r & 3) + 8 * (r >> 2) + 4 * lh;
        int sw = (l31 & 7) << 4;
        *(bf16_t*)((char*)ob + l31 * 128 + ((drow * 2) ^ sw))        = (bf16_t)(y0[r] * invl);
        *(bf16_t*)((char*)ob + l31 * 128 + (((32 + drow) * 2) ^ sw)) = (bf16_t)(y1[r] * invl);
    }
    __syncthreads();
    bf16_t* Yb = Y + (size_t)b * TT * CC + h * 64;
    #pragma unroll
    for (int i = 0; i < 4; ++i) {
        int qr = i * 8 + (l >> 3);      // row within this wave's 32
        int c  = ((l & 7) * 16) ^ ((qr & 7) << 4);
        bf16x8 v = *(const bf16x8*)((const char*)ob + qr * 128 + c);
        *(bf16x8*)&Yb[(size_t)(q0 + qr) * CC + (l & 7) * 8] = v;
    }
}

extern "C" void kernel_launch(void* const* d_in, const int* in_sizes, int n_in,
                              void* d_out, int out_size, void* d_ws, size_t ws_size,
                              hipStream_t stream) {
    const float* x   = (const float*)d_in[0];
    const float* enc = (const float*)d_in[1];
    const float* Wq  = (const float*)d_in[2];
    const float* bq  = (const float*)d_in[3];
    const float* Wk  = (const float*)d_in[4];
    const float* bk  = (const float*)d_in[5];
    const float* Wv  = (const float*)d_in[6];
    const float* bv  = (const float*)d_in[7];
    const float* Wo  = (const float*)d_in[8];
    const float* bo  = (const float*)d_in[9];

    char* w = (char*)d_ws;
    size_t o = 0;
    bf16_t* xb  = (bf16_t*)(w + o); o += (size_t)8192 * 1024 * 2;
    bf16_t* eb  = (bf16_t*)(w + o); o += (size_t)4096 * 1024 * 2;
    bf16_t* wtq = (bf16_t*)(w + o); o += (size_t)1024 * 1024 * 2;
    bf16_t* wtk = (bf16_t*)(w + o); o += (size_t)1024 * 1024 * 2;   // wtv must follow wtk
    bf16_t* wtv = (bf16_t*)(w + o); o += (size_t)1024 * 1024 * 2;
    bf16_t* wto = (bf16_t*)(w + o); o += (size_t)1024 * 1024 * 2;
    bf16_t* Qs  = (bf16_t*)(w + o); o += (size_t)8192 * 1024 * 2;
    bf16_t* Ks  = (bf16_t*)(w + o); o += (size_t)4096 * 1024 * 2;
    bf16_t* Vs  = (bf16_t*)(w + o); o += (size_t)4096 * 1024 * 2;
    bf16_t* yb  = (bf16_t*)(w + o); o += (size_t)8192 * 1024 * 2;
    bf16_t* Vt  = eb;   // eb is dead after the K/V projection; reuse for V^T (8 MB)

    cast8<<<2048, 256, 0, stream>>>(x,   xb, 8192 * 1024 / 8);
    cast8<<<1024, 256, 0, stream>>>(enc, eb, 4096 * 1024 / 8);
    transW<<<dim3(32, 32, 4), 256, 0, stream>>>(Wq, Wk, Wv, Wo, wtq, wtk, wtv, wto);

    // fold softmax scale (1/sqrt(64)) and log2(e) into Q so attention uses exp2
    const float qscale = 0.125f * 1.4426950408889634f;
    // Q proj: M=8192 (64 m-tiles), N=1024 (8 n-tiles) -> grid 512, lgNT=3, mband=8
    gemm_bt<true, false><<<512, 256, 0, stream>>>(xb, wtq, bq, nullptr, (void*)Qs, nullptr,
                                                  qscale, 3, 8);
    // fused K/V proj: M=4096 (32 m-tiles), N=2048 (16 n-tiles) -> grid 512, lgNT=4, mband=4
    gemm_bt<true, true><<<512, 256, 0, stream>>>(eb, wtk, bk, bv, (void*)Ks, (void*)Vs,
                                                 1.0f, 4, 4);

    vtrans<<<dim3(16, 64), 256, 0, stream>>>(Vs, Vt);

    attn512<<<512, 512, 0, stream>>>(Qs, Ks, Vt, yb);

    // output proj: M=8192, N=1024 -> grid 512, fp32 out
    gemm_bt<false, false><<<512, 256, 0, stream>>>(yb, wto, bo, nullptr, d_out, nullptr,
                                                   1.0f, 3, 8);
}